// Round 6
// baseline (615.929 us; speedup 1.0000x reference)
//
#include <hip/hip_runtime.h>
#include <hip/hip_bf16.h>

typedef unsigned short u16t;
typedef __attribute__((ext_vector_type(8))) short short8;
typedef __attribute__((ext_vector_type(8))) unsigned short ushort8;
typedef __attribute__((ext_vector_type(4))) unsigned short ushort4v;
typedef __attribute__((ext_vector_type(4))) float f32x4;

#define VTOT 1048576

__device__ __forceinline__ float bf2f(u16t u) {
  union { unsigned int i; float f; } v; v.i = ((unsigned int)u) << 16; return v.f;
}
__device__ __forceinline__ u16t f2bf(float f) {
  __hip_bfloat16 h = __float2bfloat16(f);
  union { __hip_bfloat16 b; u16t u; } v; v.b = h; return v.u;
}
__device__ __forceinline__ int pack2(float lo, float hi) {
  return (int)((unsigned)f2bf(lo) | ((unsigned)f2bf(hi) << 16));
}
union I4S8 { int i[4]; short8 s; ushort8 u; };

// Kernel 1: conv results in registers (per-wave z3 rows), A-frags via __shfl,
// w0 in LDS bf16. 4 barriers total; GEMM phase barrier-free.
// Block tile: 2(z1) x 2(z2) x 64(z3); 256 threads = 4 waves; wave w owns row (w>>1, w&1).
__global__ __launch_bounds__(256, 4) void nca_main(
    const float* __restrict__ xg, const float* __restrict__ w0g,
    const float* __restrict__ b0g, const float* __restrict__ w1g,
    const float* __restrict__ stg, float* __restrict__ outg,
    float* __restrict__ aws, unsigned char* __restrict__ plife)
{
  __shared__ u16t xs[8704];           // [4][4][34][16] bf16 halo (2 z3-passes); reused as hw
  __shared__ u16t w0L[128 * 72];      // w0 bf16, row stride 72 (16B-aligned, 2-way banks)
  __shared__ float alpha_l[256];      // fp32 alpha(x2) staging
  __shared__ unsigned char pl_l[256]; // pre_life staging

  const int t = threadIdx.x;
  const int bid = blockIdx.x;
  const int b = bid >> 10;
  const int z1base = ((bid >> 5) & 31) * 2;
  const int z2base = (bid & 31) * 2;
  const int lane = t & 63, w = t >> 6;

  // stage w0 -> LDS bf16 once (coalesced float4 reads)
  #pragma unroll
  for (int it = 0; it < 8; ++it) {
    int e = it * 1024 + t * 4;
    f32x4 v4 = *(const f32x4*)(w0g + e);
    ushort4v bv;
    #pragma unroll
    for (int j = 0; j < 4; ++j) bv[j] = f2bf(v4[j]);
    int n = e >> 6, k = e & 63;
    *(ushort4v*)(w0L + n * 72 + k) = bv;
  }

  // conv outputs, packed bf16 pairs: [pass][4 ints] per type
  int px_[2][4], pcx[2][4], pcy[2][4], pcz[2][4];
  const int z1 = w >> 1, z2 = w & 1, z3l = lane >> 1, hc = lane & 1;

  #pragma unroll
  for (int p = 0; p < 2; ++p) {
    if (p) __syncthreads();  // xs WAR vs previous pass conv reads
    // stage x halo (fp32 -> bf16): 544 rows x 16 ch = 2176 float4 chunks
    for (int it = 0; it < 9; ++it) {
      int q = t + it * 256;
      if (q < 2176) {
        int c4 = (q & 3) * 4, s = q >> 2;
        int i3 = s % 34, r = s / 34;
        int i2 = r & 3, i1 = r >> 2;
        int z1g = z1base + i1 - 1, z2g = z2base + i2 - 1, z3g = p * 32 + i3 - 1;
        f32x4 val = {0.f, 0.f, 0.f, 0.f};
        if ((unsigned)z1g < 64u && (unsigned)z2g < 64u && (unsigned)z3g < 64u) {
          int gv = ((b * 64 + z1g) * 64 + z2g) * 64 + z3g;
          val = *(const f32x4*)(xg + gv * 16 + c4);
        }
        ushort4v bv;
        #pragma unroll
        for (int j = 0; j < 4; ++j) bv[j] = f2bf(val[j]);
        *(ushort4v*)(xs + s * 16 + c4) = bv;
      }
    }
    __syncthreads();
    // conv: wave-local voxel v_loc = z3l + 32p, half-channel hc
    {
      float ax[8], ay[8], az[8];
      #pragma unroll
      for (int c = 0; c < 8; ++c) { ax[c] = 0.f; ay[c] = 0.f; az[c] = 0.f; }
      I4S8 ctr; ctr.i[0] = ctr.i[1] = ctr.i[2] = ctr.i[3] = 0;
      float amax = 0.0f;  // alpha>=0; 0-pad same >0.1 verdict as -inf pad
      const float W[3] = {1.f, 2.f, 1.f};
      const float D[3] = {-1.f, 0.f, 1.f};
      #pragma unroll
      for (int d1 = 0; d1 < 3; ++d1)
        #pragma unroll
        for (int d2 = 0; d2 < 3; ++d2)
          #pragma unroll
          for (int d3 = 0; d3 < 3; ++d3) {
            const int base = (((z1 + d1) * 4 + (z2 + d2)) * 34 + (z3l + d3)) * 16 + hc * 8;
            I4S8 uu; uu.u = *(const ushort8*)(xs + base);
            float f[8];
            #pragma unroll
            for (int c = 0; c < 8; ++c) f[c] = bf2f((u16t)uu.u[c]);
            const float cx = W[d1] * W[d2] * D[d3] * 0.03125f;  // kx[k,i,j]=w[k]w[i]d[j]/32
            const float cy = W[d1] * D[d2] * W[d3] * 0.03125f;  // ky=kx.T(0,2,1)
            const float cz = D[d1] * W[d2] * W[d3] * 0.03125f;  // kz=kx.T(2,1,0)
            if (cx != 0.f) {
              #pragma unroll
              for (int c = 0; c < 8; ++c) ax[c] = fmaf(f[c], cx, ax[c]);
            }
            if (cy != 0.f) {
              #pragma unroll
              for (int c = 0; c < 8; ++c) ay[c] = fmaf(f[c], cy, ay[c]);
            }
            if (cz != 0.f) {
              #pragma unroll
              for (int c = 0; c < 8; ++c) az[c] = fmaf(f[c], cz, az[c]);
            }
            if (d1 == 1 && d2 == 1 && d3 == 1) ctr = uu;
            amax = fmaxf(amax, f[3]);  // alpha = ch3 (meaningful for hc==0)
          }
      #pragma unroll
      for (int i = 0; i < 4; ++i) {
        px_[p][i] = ctr.i[i];
        pcx[p][i] = pack2(ax[2 * i], ax[2 * i + 1]);
        pcy[p][i] = pack2(ay[2 * i], ay[2 * i + 1]);
        pcz[p][i] = pack2(az[2 * i], az[2 * i + 1]);
      }
      if (hc == 0) pl_l[w * 64 + z3l + 32 * p] = (amax > 0.1f) ? (unsigned char)1 : (unsigned char)0;
    }
  }
  __syncthreads();  // conv done everywhere; xs repurposed as hw; w0L staged

  // GEMM phase: per wave M=64 (4 m-tiles); fc0 K=64 N=128 (B from w0L); fc1 K=128 N=16
  {
    const int col = lane & 15, quad = lane >> 4;
    short8 w1f[4];  // B[k=kt*32+quad*8+j][n=col] = w1[col][k], fp32->bf16
    #pragma unroll
    for (int kt = 0; kt < 4; ++kt) {
      const float* p = w1g + col * 128 + kt * 32 + quad * 8;
      f32x4 lo = *(const f32x4*)p, hi = *(const f32x4*)(p + 4);
      short8 fr;
      #pragma unroll
      for (int j = 0; j < 4; ++j) { fr[j] = (short)f2bf(lo[j]); fr[4 + j] = (short)f2bf(hi[j]); }
      w1f[kt] = fr;
    }
    float bias[8];
    #pragma unroll
    for (int nt = 0; nt < 8; ++nt) bias[nt] = b0g[nt * 16 + col];

    u16t* hw = xs + w * 2176;  // per-wave h buffer [16][136]

    #pragma unroll
    for (int mt = 0; mt < 4; ++mt) {
      const int pp = mt >> 1;
      const int src = (((mt * 16 + col) & 31) << 1) | (quad & 1);
      const bool hiq = quad >= 2;
      // A-frags via in-wave shfl: kt0 = {x | convX}, kt1 = {convY | convZ}
      I4S8 a0, a1;
      #pragma unroll
      for (int i = 0; i < 4; ++i) {
        int vx = __shfl(px_[pp][i], src, 64);
        int vc = __shfl(pcx[pp][i], src, 64);
        a0.i[i] = hiq ? vc : vx;
        int vy = __shfl(pcy[pp][i], src, 64);
        int vz = __shfl(pcz[pp][i], src, 64);
        a1.i[i] = hiq ? vz : vy;
      }
      f32x4 acc[8];
      #pragma unroll
      for (int nt = 0; nt < 8; ++nt) {
        f32x4 tmp = {bias[nt], bias[nt], bias[nt], bias[nt]};
        acc[nt] = tmp;
      }
      #pragma unroll
      for (int nt = 0; nt < 8; ++nt) {
        short8 bf = *(const short8*)(w0L + (nt * 16 + col) * 72 + quad * 8);
        acc[nt] = __builtin_amdgcn_mfma_f32_16x16x32_bf16(a0.s, bf, acc[nt], 0, 0, 0);
      }
      #pragma unroll
      for (int nt = 0; nt < 8; ++nt) {
        short8 bf = *(const short8*)(w0L + (nt * 16 + col) * 72 + 32 + quad * 8);
        acc[nt] = __builtin_amdgcn_mfma_f32_16x16x32_bf16(a1.s, bf, acc[nt], 0, 0, 0);
      }
      // relu -> bf16 -> hw (C layout -> A layout); h[m=quad*4+r][k=nt*16+col]
      #pragma unroll
      for (int nt = 0; nt < 8; ++nt)
        #pragma unroll
        for (int r = 0; r < 4; ++r)
          hw[(quad * 4 + r) * 136 + nt * 16 + col] = f2bf(fmaxf(acc[nt][r], 0.0f));
      __threadfence_block();  // wave-local write->read ordering
      f32x4 dxa = {0.f, 0.f, 0.f, 0.f};
      #pragma unroll
      for (int kt = 0; kt < 4; ++kt) {
        short8 ah = *(const short8*)(hw + col * 136 + kt * 32 + quad * 8);
        dxa = __builtin_amdgcn_mfma_f32_16x16x32_bf16(ah, w1f[kt], dxa, 0, 0, 0);
      }
      __threadfence_block();  // WAR: next mt rewrites hw
      // epilogue: v_loc = mt*16+quad*4+r is this wave's z3
      #pragma unroll
      for (int r = 0; r < 4; ++r) {
        const int vl = mt * 16 + quad * 4 + r;
        const int gv = ((b * 64 + z1base + z1) * 64 + (z2base + z2)) * 64 + vl;
        const int addr = gv * 16 + col;
        float stv = stg[gv];  // broadcast across cols, L1-hot
        float dx = (stv > 0.5f) ? dxa[r] : 0.0f;
        float x2 = xg[addr] + dx;  // xg re-read L3-hot
        outg[addr] = x2;
        if (col == 3) alpha_l[w * 64 + vl] = x2;
      }
    }
  }
  __threadfence_block();  // alpha_l/pl_l are wave-local: waitcnt suffices, no barrier
  if (aws != nullptr) {
    const int gv = ((b * 64 + z1base + z1) * 64 + (z2base + z2)) * 64 + (lane | 0);
    const int gvf = ((b * 64 + z1base + (t >> 7)) * 64 + (z2base + ((t >> 6) & 1))) * 64 + (t & 63);
    (void)gv;
    aws[gvf] = alpha_l[t];
    plife[gvf] = pl_l[t];
  }
}

// Kernel 2 (compact): life = plife & (maxpool3(aws) > 0.1); zero dead voxels in out.
__global__ void nca_life(const float* __restrict__ aws,
                         const unsigned char* __restrict__ plife,
                         float* __restrict__ og)
{
  __shared__ float a2[1056];  // [4][4][66] alpha(x2)
  const int t = threadIdx.x, bid = blockIdx.x;
  const int b = bid >> 10;
  const int z1base = ((bid >> 5) & 31) * 2;
  const int z2base = (bid & 31) * 2;
  for (int it = 0; it < 5; ++it) {
    int q = t + it * 256;
    if (q < 1056) {
      int i3 = q % 66, r = q / 66;
      int i2 = r & 3, i1 = r >> 2;
      int z1g = z1base + i1 - 1, z2g = z2base + i2 - 1, z3g = i3 - 1;
      float vo = 0.f;  // 0 pad: 0 > 0.1 false, same verdict as -inf pad
      if ((unsigned)z1g < 64u && (unsigned)z2g < 64u && (unsigned)z3g < 64u)
        vo = aws[((b * 64 + z1g) * 64 + z2g) * 64 + z3g];
      a2[q] = vo;
    }
  }
  __syncthreads();
  const int z1 = t >> 7, z2 = (t >> 6) & 1, z3 = t & 63;
  float mo = -1e30f;
  #pragma unroll
  for (int d1 = 0; d1 < 3; ++d1)
    #pragma unroll
    for (int d2 = 0; d2 < 3; ++d2)
      #pragma unroll
      for (int d3 = 0; d3 < 3; ++d3)
        mo = fmaxf(mo, a2[((z1 + d1) * 4 + (z2 + d2)) * 66 + (z3 + d3)]);
  const int gv = ((b * 64 + z1base + z1) * 64 + (z2base + z2)) * 64 + z3;
  const bool life = (plife[gv] != 0) && (mo > 0.1f);
  if (!life) {
    f32x4 z = {0.f, 0.f, 0.f, 0.f};
    #pragma unroll
    for (int j = 0; j < 4; ++j) *(f32x4*)(og + gv * 16 + j * 4) = z;
  }
}

// Fallback (no workspace): recompute both alive masks from strided global reads.
__global__ void nca_life_strided(const float* __restrict__ xg, const float* __restrict__ outg,
                                 float* __restrict__ og)
{
  __shared__ float a2x[1056];
  __shared__ float a2o[1056];
  const int t = threadIdx.x, bid = blockIdx.x;
  const int b = bid >> 10;
  const int z1base = ((bid >> 5) & 31) * 2;
  const int z2base = (bid & 31) * 2;
  for (int it = 0; it < 5; ++it) {
    int q = t + it * 256;
    if (q < 1056) {
      int i3 = q % 66, r = q / 66;
      int i2 = r & 3, i1 = r >> 2;
      int z1g = z1base + i1 - 1, z2g = z2base + i2 - 1, z3g = i3 - 1;
      float vx = 0.f, vo = 0.f;
      if ((unsigned)z1g < 64u && (unsigned)z2g < 64u && (unsigned)z3g < 64u) {
        int gv = ((b * 64 + z1g) * 64 + z2g) * 64 + z3g;
        vx = xg[gv * 16 + 3];
        vo = outg[gv * 16 + 3];
      }
      a2x[q] = vx; a2o[q] = vo;
    }
  }
  __syncthreads();
  const int z1 = t >> 7, z2 = (t >> 6) & 1, z3 = t & 63;
  float mx = -1e30f, mo = -1e30f;
  #pragma unroll
  for (int d1 = 0; d1 < 3; ++d1)
    #pragma unroll
    for (int d2 = 0; d2 < 3; ++d2)
      #pragma unroll
      for (int d3 = 0; d3 < 3; ++d3) {
        const int idx = ((z1 + d1) * 4 + (z2 + d2)) * 66 + (z3 + d3);
        mx = fmaxf(mx, a2x[idx]);
        mo = fmaxf(mo, a2o[idx]);
      }
  const bool life = (mx > 0.1f) && (mo > 0.1f);
  if (!life) {
    const int gv = ((b * 64 + z1base + z1) * 64 + (z2base + z2)) * 64 + z3;
    f32x4 z = {0.f, 0.f, 0.f, 0.f};
    #pragma unroll
    for (int j = 0; j < 4; ++j) *(f32x4*)(og + gv * 16 + j * 4) = z;
  }
}

extern "C" void kernel_launch(void* const* d_in, const int* in_sizes, int n_in,
                              void* d_out, int out_size, void* d_ws, size_t ws_size,
                              hipStream_t stream) {
  (void)out_size;
  const void *px = nullptr, *pw0 = nullptr, *pb0 = nullptr, *pw1 = nullptr, *pst = nullptr;
  for (int i = 0; i < n_in; ++i) {
    switch (in_sizes[i]) {
      case 16777216: px  = d_in[i]; break;  // x  [4,64,64,64,16]
      case 8192:     pw0 = d_in[i]; break;  // w0 [128,64]
      case 128:      pb0 = d_in[i]; break;  // b0 [128]
      case 2048:     pw1 = d_in[i]; break;  // w1 [16,128]
      case 1048576:  pst = d_in[i]; break;  // stoch [4,64,64,64,1]
    }
  }
  if (!px || !pw0 || !pb0 || !pw1 || !pst) {
    px = d_in[0]; pw0 = d_in[1]; pb0 = d_in[2]; pw1 = d_in[3]; pst = d_in[4];
  }
  float* outg = (float*)d_out;
  const size_t need = (size_t)VTOT * 4 + (size_t)VTOT;  // fp32 alpha + byte plife
  const bool use_ws = (d_ws != nullptr) && (ws_size >= need);
  float* aws = use_ws ? (float*)d_ws : nullptr;
  unsigned char* plife = use_ws ? ((unsigned char*)d_ws + (size_t)VTOT * 4) : nullptr;

  nca_main<<<4096, 256, 0, stream>>>((const float*)px, (const float*)pw0, (const float*)pb0,
                                     (const float*)pw1, (const float*)pst, outg, aws, plife);
  if (use_ws)
    nca_life<<<4096, 256, 0, stream>>>(aws, plife, outg);
  else
    nca_life_strided<<<4096, 256, 0, stream>>>((const float*)px, outg, outg);
}